// Round 3
// baseline (202.134 us; speedup 1.0000x reference)
//
#include <hip/hip_runtime.h>

#define NB 8
#define NT 64
#define NS 128
#define TDIM 512
#define NV 32000
#define NEXT 32256
#define NBT 512
#define LNEPS 1e-5f

typedef unsigned short u16;
typedef __attribute__((ext_vector_type(8))) short short8;
typedef __attribute__((ext_vector_type(4))) float f32x4;

__device__ __forceinline__ float bf2f(u16 u){ union{unsigned int i; float f;} v; v.i = ((unsigned int)u)<<16; return v.f; }
__device__ __forceinline__ u16 f2bf(float f){ union{float f; unsigned int i;} v; v.f=f; unsigned int r = v.i + 0x7FFFu + ((v.i>>16)&1u); return (u16)(r>>16); }
__device__ __forceinline__ float wsum(float v){
  v += __shfl_xor(v,32); v += __shfl_xor(v,16); v += __shfl_xor(v,8);
  v += __shfl_xor(v,4);  v += __shfl_xor(v,2);  v += __shfl_xor(v,1); return v; }
__device__ __forceinline__ float wmax(float v){
  v = fmaxf(v,__shfl_xor(v,32)); v = fmaxf(v,__shfl_xor(v,16)); v = fmaxf(v,__shfl_xor(v,8));
  v = fmaxf(v,__shfl_xor(v,4));  v = fmaxf(v,__shfl_xor(v,2));  v = fmaxf(v,__shfl_xor(v,1)); return v; }

#define GL2LDS(gp, lp) __builtin_amdgcn_global_load_lds( \
    (__attribute__((address_space(1))) void*)(void*)(gp), \
    (__attribute__((address_space(3))) void*)(void*)(lp), 16, 0, 0)

// ---------------- f32 -> bf16 cast of GEMM operands ----------------
__global__ __launch_bounds__(256) void k_cast(const float* tgt, const float* s1, const float* s2,
    const float* a1w, const float* a2w, const float* ofw,
    u16* tgtb, u16* s1b, u16* s2b, u16* a1wb, u16* a2wb, u16* ofwb)
{
  int blk = blockIdx.x;
  const float* src; u16* dst; int base;
  if(blk < 128){       src=tgt; dst=tgtb;  base=blk; }
  else if(blk < 384){  src=s1;  dst=s1b;   base=blk-128; }
  else if(blk < 640){  src=s2;  dst=s2b;   base=blk-384; }
  else if(blk < 896){  src=a1w; dst=a1wb;  base=blk-640; }
  else if(blk < 1152){ src=a2w; dst=a2wb;  base=blk-896; }
  else {               src=ofw; dst=ofwb;  base=blk-1152; }
  size_t off = (size_t)base*2048 + (size_t)threadIdx.x*8;
  float4 x0 = *(const float4*)(src+off);
  float4 x1 = *(const float4*)(src+off+4);
  float xs[8] = {x0.x,x0.y,x0.z,x0.w,x1.x,x1.y,x1.z,x1.w};
  short8 r;
  #pragma unroll
  for(int j=0;j<8;++j) r[j] = (short)f2bf(xs[j]);
  *(short8*)(dst+off) = r;
}

// ---------------- masks ----------------
__global__ __launch_bounds__(256) void k_masks(const float* tgt, const float* s1, const float* s2, float* msk){
  int row = blockIdx.x*4 + (threadIdx.x>>6);
  int lane = threadIdx.x&63;
  const float* p;
  if(row < 512)       p = tgt + (size_t)row*TDIM;
  else if(row < 1536) p = s1  + (size_t)(row-512)*TDIM;
  else                p = s2  + (size_t)(row-1536)*TDIM;
  float4 u = ((const float4*)p)[lane];
  float4 v = ((const float4*)p)[lane+64];
  float a = fabsf(u.x)+fabsf(u.y)+fabsf(u.z)+fabsf(u.w)
          + fabsf(v.x)+fabsf(v.y)+fabsf(v.z)+fabsf(v.w);
  a = wsum(a);
  if(lane==0) msk[row] = (a>0.f) ? 1.f : 0.f;
}

// ---------------- MFMA GEMM core: C[M,N] = A[M,K] * W[N,K]^T ----------------
// 128x128 tile, 4 waves (2x2), each wave 64x64 (4x4 frags of 16x16x32).
template<int MODE> // 0: f32 out, 1: bf16 out + f32 bias
__device__ __forceinline__ void gemm_core(const u16* A, int lda, const u16* W, int ldw,
    float* Cf, u16* Cb, int ldc, const float* bias, int K, int bm, int bn)
{
  __shared__ u16 Al[128*32];
  __shared__ u16 Wl[128*32];
  const int tid = threadIdx.x, lane = tid&63, wv = tid>>6;
  const int wm = wv>>1, wn = wv&1;
  const int fr = lane&15, fq = lane>>4;
  const int lrow = lane>>2;        // 0..15 within chunk
  const int lcol = (lane&3)*8;     // k-offset elements
  f32x4 acc[4][4] = {};
  for(int k0=0;k0<K;k0+=32){
    #pragma unroll
    for(int r=0;r<2;++r){
      int c = wv + 4*r;            // chunk 0..7, wave-uniform
      int row = c*16 + lrow;
      const u16* ga = A + (size_t)(bm+row)*lda + k0 + lcol;
      const u16* gw = W + (size_t)(bn+row)*ldw + k0 + lcol;
      GL2LDS(ga, &Al[c*512]);
      GL2LDS(gw, &Wl[c*512]);
    }
    __syncthreads();
    short8 af[4], bfr[4];
    #pragma unroll
    for(int m=0;m<4;++m) af[m] = *(const short8*)&Al[(wm*64 + m*16 + fr)*32 + fq*8];
    #pragma unroll
    for(int n=0;n<4;++n) bfr[n] = *(const short8*)&Wl[(wn*64 + n*16 + fr)*32 + fq*8];
    #pragma unroll
    for(int m=0;m<4;++m)
      #pragma unroll
      for(int n=0;n<4;++n)
        acc[m][n] = __builtin_amdgcn_mfma_f32_16x16x32_bf16(af[m], bfr[n], acc[m][n], 0,0,0);
    __syncthreads();
  }
  #pragma unroll
  for(int m=0;m<4;++m)
    #pragma unroll
    for(int n=0;n<4;++n)
      #pragma unroll
      for(int i=0;i<4;++i){
        int row = bm + wm*64 + m*16 + fq*4 + i;
        int col = bn + wn*64 + n*16 + fr;
        if(MODE==0) Cf[(size_t)row*ldc + col] = acc[m][n][i];
        else        Cb[(size_t)row*ldc + col] = f2bf(acc[m][n][i] + bias[col]);
      }
}

__global__ __launch_bounds__(256) void k_proj(const u16* tgt, const u16* s1, const u16* s2,
    const u16* w1, const u16* w2, float* sq1, float* sk1, float* sq2, float* sk2)
{
  int z = blockIdx.z;
  int Mt = (z&1) ? 1024 : 512;
  int bm = blockIdx.y*128; if(bm >= Mt) return;
  const u16* A = (z&1) ? ((z>>1) ? s2 : s1) : tgt;
  const u16* W = ((z>>1) ? w2 : w1) + ((z&1) ? TDIM : 0);
  float* Cf = (z==0) ? sq1 : (z==1) ? sk1 : (z==2) ? sq2 : sk2;
  gemm_core<0>(A, TDIM, W, 2*TDIM, Cf, nullptr, TDIM, nullptr, TDIM, bm, blockIdx.x*128);
}

__global__ __launch_bounds__(256) void k_big(const u16* tgt, const u16* W, const float* bias, u16* logits)
{
  gemm_core<1>(tgt, TDIM, W, TDIM, nullptr, logits, NV, bias, TDIM, blockIdx.x*128, blockIdx.y*128);
}

// ---------------- fused attention (both sources) + gate ----------------
__global__ __launch_bounds__(256) void k_attn(
  const float* tgt, const float* k1g, const float* k2g,
  const float* b1, const float* v1, const float* b2, const float* v2,
  const float* gw, const float* gb,
  const float* sq1, const float* sk1, const float* sq2, const float* sk2,
  const float* msk, float* attln1, float* attln2, float* pws)
{
  int bt = blockIdx.x, b = bt>>6;
  int tid = threadIdx.x, lane = tid&63, wv = tid>>6;
  __shared__ float sq_s[512], v_s[512], c_s[2][512], sc_s[128], aw_s[128], km_s[128], st_s[4], gl_s[3];
  float qm = msk[bt];
  for(int src=0; src<2; ++src){
    const float* SQ = src ? sq2 : sq1;
    const float* SK = src ? sk2 : sk1;
    const float* bb = src ? b2 : b1;
    const float* vvp = src ? v2 : v1;
    const float* kg = src ? k2g : k1g;
    const float* km_g = msk + 512 + src*1024 + b*128;
    for(int e=tid; e<512; e+=256){ sq_s[e] = SQ[(size_t)bt*512+e] + bb[e]; v_s[e] = vvp[e]; }
    for(int s=tid; s<128; s+=256) km_s[s] = km_g[s];
    __syncthreads();
    // scores[s] = sum_e v[e]*tanh(sq[e]+sk[s,e])
    for(int s=wv; s<128; s+=4){
      const float* skrow = SK + ((size_t)b*128 + s)*512;
      float acc = 0.f;
      #pragma unroll
      for(int r=0;r<8;++r){
        int e = lane + 64*r;
        float x = sq_s[e] + skrow[e];
        x = fminf(fmaxf(x, -30.f), 30.f);
        float ex = __expf(2.f*x);
        acc += v_s[e] * ((ex-1.f)/(ex+1.f));
      }
      acc = wsum(acc);
      if(lane==0) sc_s[s] = acc;
    }
    __syncthreads();
    if(wv==0){
      float a0 = sc_s[lane]*km_s[lane]*qm, a1 = sc_s[lane+64]*km_s[lane+64]*qm;
      float sm = wsum(a0+a1), sqq = wsum(a0*a0+a1*a1);
      float m0 = km_s[lane]    != 0.f ? sc_s[lane]    : -1e30f;
      float m1 = km_s[lane+64] != 0.f ? sc_s[lane+64] : -1e30f;
      float mx = wmax(fmaxf(m0,m1));
      float e0 = km_s[lane]    != 0.f ? __expf(sc_s[lane]-mx)    : 0.f;
      float e1 = km_s[lane+64] != 0.f ? __expf(sc_s[lane+64]-mx) : 0.f;
      float den = wsum(e0+e1);
      if(lane==0){
        float mean = sm/128.f;
        float var  = sqq/128.f - mean*mean;
        st_s[0]=mean; st_s[1]=rsqrtf(var+LNEPS); st_s[2]=mx; st_s[3]=den;
      }
    }
    __syncthreads();
    if(tid<128){
      float mean=st_s[0], inv=st_s[1], mx=st_s[2], den=st_s[3];
      float av = sc_s[tid]*km_s[tid]*qm;
      (src ? attln2 : attln1)[(size_t)bt*128 + tid] = (av-mean)*inv;
      aw_s[tid] = km_s[tid] != 0.f ? __expf(sc_s[tid]-mx)/den : 0.f;
    }
    __syncthreads();
    for(int d=tid; d<512; d+=256){
      float acc = 0.f;
      #pragma unroll 8
      for(int s=0;s<128;++s) acc += aw_s[s]*kg[((size_t)b*128+s)*512 + d];
      c_s[src][d] = qm*acc;
    }
    __syncthreads();
  }
  // gate
  if(wv<3){
    int p = wv; float acc = 0.f;
    for(int j=0;j<24;++j){
      int d = lane + 64*j; float gi;
      if(d<512)        gi = tgt[(size_t)bt*512 + d];
      else if(d<1024)  gi = c_s[0][d-512];
      else             gi = c_s[1][d-1024];
      acc += gw[p*1536 + d] * gi;
    }
    acc = wsum(acc);
    if(lane==0) gl_s[p] = acc + gb[p];
  }
  __syncthreads();
  if(tid==0){
    float m = fmaxf(gl_s[0], fmaxf(gl_s[1], gl_s[2]));
    float e0=__expf(gl_s[0]-m), e1=__expf(gl_s[1]-m), e2=__expf(gl_s[2]-m);
    float s = e0+e1+e2;
    pws[bt*4+0]=e0/s; pws[bt*4+1]=e1/s; pws[bt*4+2]=e2/s;
  }
}

// ---------------- logits row stats ----------------
__global__ __launch_bounds__(256) void k_stats(const u16* logits, float* stats){
  int row = blockIdx.x, tid = threadIdx.x, lane = tid&63, wv = tid>>6;
  const u16* Lr = logits + (size_t)row*NV;
  float s=0.f, ss=0.f;
  for(int vb=tid; vb<NV/8; vb+=256){
    short8 x = *(const short8*)&Lr[vb*8];
    #pragma unroll
    for(int j=0;j<8;++j){ float f = bf2f((u16)x[j]); s += f; ss += f*f; }
  }
  __shared__ float rs[4], rss[4];
  s = wsum(s); ss = wsum(ss);
  if(lane==0){ rs[wv]=s; rss[wv]=ss; }
  __syncthreads();
  if(tid==0){
    float S=rs[0]+rs[1]+rs[2]+rs[3], SS=rss[0]+rss[1]+rss[2]+rss[3];
    float mean = S/(float)NV;
    float var  = SS/(float)NV - mean*mean;
    stats[row*2]   = mean;
    stats[row*2+1] = rsqrtf(var+LNEPS);
  }
}

// ---------------- final: out = p0 * LN(logits), pad zeros (f32 out) ----------------
__global__ __launch_bounds__(256) void k_final(const u16* logits, const float* stats, const float* pws, float* out){
  int gid = blockIdx.x*256 + threadIdx.x;     // float4 id: 512 * 8064
  int row = gid / (NEXT/4);
  int e0  = (gid % (NEXT/4))*4;
  float4 r;
  if(e0 < NV){
    float mean = stats[row*2], inv = stats[row*2+1], p0 = pws[row*4];
    const u16* L = &logits[(size_t)row*NV + e0];
    r.x = p0*(bf2f(L[0])-mean)*inv;
    r.y = p0*(bf2f(L[1])-mean)*inv;
    r.z = p0*(bf2f(L[2])-mean)*inv;
    r.w = p0*(bf2f(L[3])-mean)*inv;
  } else {
    r.x = r.y = r.z = r.w = 0.f;
  }
  *(float4*)&out[(size_t)row*NEXT + e0] = r;
}

// ---------------- scatter patch: out[bt, map[b,s]] += p_src * att_ln (f32) ----------------
__global__ __launch_bounds__(256) void k_scatter(const int* map1, const int* map2,
   const float* attln1, const float* attln2, const float* pws, float* out){
  int bt = blockIdx.x, b = bt>>6, i = threadIdx.x;
  __shared__ int e_s[256]; __shared__ float v_s[256];
  int src = i>>7, s = i&127;
  int e = (src ? map2 : map1)[b*128 + s];
  float val = pws[bt*4 + 1 + src] * (src ? attln2 : attln1)[(size_t)bt*128 + s];
  e_s[i] = e; v_s[i] = val;
  __syncthreads();
  bool leader = true;
  for(int j=0;j<i;++j) if(e_s[j]==e){ leader=false; break; }
  if(leader){
    float tot = 0.f;
    for(int j=i;j<256;++j) if(e_s[j]==e) tot += v_s[j];
    out[(size_t)bt*NEXT + e] += tot;
  }
}

extern "C" void kernel_launch(void* const* d_in, const int* in_sizes, int n_in,
                              void* d_out, int out_size, void* d_ws, size_t ws_size,
                              hipStream_t stream)
{
  const float* tgt  = (const float*)d_in[0];
  const float* s1k  = (const float*)d_in[1];
  const float* s2k  = (const float*)d_in[2];
  const int*   map1 = (const int*)d_in[3];
  const int*   map2 = (const int*)d_in[4];
  const float* ofw  = (const float*)d_in[5];
  const float* ofb  = (const float*)d_in[6];
  const float* a1w  = (const float*)d_in[7];
  const float* a1b  = (const float*)d_in[8];
  const float* v1   = (const float*)d_in[9];
  const float* a2w  = (const float*)d_in[10];
  const float* a2b  = (const float*)d_in[11];
  const float* v2   = (const float*)d_in[12];
  const float* gw   = (const float*)d_in[13];
  const float* gb   = (const float*)d_in[14];

  float* wsf   = (float*)d_ws;
  float* sq1   = wsf;                   // 262144
  float* sq2   = wsf + 262144;
  float* sk1   = wsf + 524288;          // 524288
  float* sk2   = wsf + 1048576;
  float* al1   = wsf + 1572864;         // 65536
  float* al2   = wsf + 1638400;
  float* pws   = wsf + 1703936;         // 2048
  float* msk   = wsf + 1705984;         // 2560
  float* stats = wsf + 1708544;         // 1024
  u16*  logits = (u16*)(wsf + 1709568); // 512*32000 bf16
  u16*  tgtb   = (u16*)(wsf + 9901568);
  u16*  s1b    = (u16*)(wsf + 10032640);
  u16*  s2b    = (u16*)(wsf + 10294784);
  u16*  a1wb   = (u16*)(wsf + 10556928);
  u16*  a2wb   = (u16*)(wsf + 10819072);
  u16*  ofwb   = (u16*)(wsf + 11081216); // ends at float offset 19273216 (~77 MB)
  float* out   = (float*)d_out;

  k_cast   <<<9152, 256, 0, stream>>>(tgt, s1k, s2k, a1w, a2w, ofw, tgtb, s1b, s2b, a1wb, a2wb, ofwb);
  k_masks  <<<640, 256, 0, stream>>>(tgt, s1k, s2k, msk);
  k_proj   <<<dim3(4,8,4), 256, 0, stream>>>(tgtb, s1b, s2b, a1wb, a2wb, sq1, sk1, sq2, sk2);
  k_big    <<<dim3(4,250), 256, 0, stream>>>(tgtb, ofwb, ofb, logits);
  k_attn   <<<512, 256, 0, stream>>>(tgt, s1k, s2k, a1b, v1, a2b, v2, gw, gb,
                                     sq1, sk1, sq2, sk2, msk, al1, al2, pws);
  k_stats  <<<512, 256, 0, stream>>>(logits, stats);
  k_final  <<<NBT*(NEXT/4)/256, 256, 0, stream>>>(logits, stats, pws, out);
  k_scatter<<<512, 256, 0, stream>>>(map1, map2, al1, al2, pws, out);
}

// Round 4
// 154.356 us; speedup vs baseline: 1.3095x; 1.3095x over previous
//
#include <hip/hip_runtime.h>

#define NB 8
#define NT 64
#define NS 128
#define TDIM 512
#define NV 32000
#define NEXT 32256
#define NBT 512
#define LNEPS 1e-5f

typedef unsigned short u16;
typedef __attribute__((ext_vector_type(8))) short short8;
typedef __attribute__((ext_vector_type(4))) float f32x4;

__device__ __forceinline__ float bf2f(u16 u){ union{unsigned int i; float f;} v; v.i = ((unsigned int)u)<<16; return v.f; }
__device__ __forceinline__ u16 f2bf(float f){ union{float f; unsigned int i;} v; v.f=f; unsigned int r = v.i + 0x7FFFu + ((v.i>>16)&1u); return (u16)(r>>16); }
__device__ __forceinline__ float wsum(float v){
  v += __shfl_xor(v,32); v += __shfl_xor(v,16); v += __shfl_xor(v,8);
  v += __shfl_xor(v,4);  v += __shfl_xor(v,2);  v += __shfl_xor(v,1); return v; }
__device__ __forceinline__ float wmax(float v){
  v = fmaxf(v,__shfl_xor(v,32)); v = fmaxf(v,__shfl_xor(v,16)); v = fmaxf(v,__shfl_xor(v,8));
  v = fmaxf(v,__shfl_xor(v,4));  v = fmaxf(v,__shfl_xor(v,2));  v = fmaxf(v,__shfl_xor(v,1)); return v; }

#define GL2LDS(gp, lp) __builtin_amdgcn_global_load_lds( \
    (__attribute__((address_space(1))) void*)(void*)(gp), \
    (__attribute__((address_space(3))) void*)(void*)(lp), 16, 0, 0)

// ---------------- f32 -> bf16 cast of GEMM operands ----------------
__global__ __launch_bounds__(256) void k_cast(const float* tgt, const float* s1, const float* s2,
    const float* a1w, const float* a2w, const float* ofw,
    u16* tgtb, u16* s1b, u16* s2b, u16* a1wb, u16* a2wb, u16* ofwb)
{
  int blk = blockIdx.x;
  const float* src; u16* dst; int base;
  if(blk < 128){       src=tgt; dst=tgtb;  base=blk; }
  else if(blk < 384){  src=s1;  dst=s1b;   base=blk-128; }
  else if(blk < 640){  src=s2;  dst=s2b;   base=blk-384; }
  else if(blk < 896){  src=a1w; dst=a1wb;  base=blk-640; }
  else if(blk < 1152){ src=a2w; dst=a2wb;  base=blk-896; }
  else {               src=ofw; dst=ofwb;  base=blk-1152; }
  size_t off = (size_t)base*2048 + (size_t)threadIdx.x*8;
  float4 x0 = *(const float4*)(src+off);
  float4 x1 = *(const float4*)(src+off+4);
  float xs[8] = {x0.x,x0.y,x0.z,x0.w,x1.x,x1.y,x1.z,x1.w};
  short8 r;
  #pragma unroll
  for(int j=0;j<8;++j) r[j] = (short)f2bf(xs[j]);
  *(short8*)(dst+off) = r;
}

// ---------------- masks ----------------
__global__ __launch_bounds__(256) void k_masks(const float* tgt, const float* s1, const float* s2, float* msk){
  int row = blockIdx.x*4 + (threadIdx.x>>6);
  int lane = threadIdx.x&63;
  const float* p;
  if(row < 512)       p = tgt + (size_t)row*TDIM;
  else if(row < 1536) p = s1  + (size_t)(row-512)*TDIM;
  else                p = s2  + (size_t)(row-1536)*TDIM;
  float4 u = ((const float4*)p)[lane];
  float4 v = ((const float4*)p)[lane+64];
  float a = fabsf(u.x)+fabsf(u.y)+fabsf(u.z)+fabsf(u.w)
          + fabsf(v.x)+fabsf(v.y)+fabsf(v.z)+fabsf(v.w);
  a = wsum(a);
  if(lane==0) msk[row] = (a>0.f) ? 1.f : 0.f;
}

// ---------------- MFMA GEMM core: C[M,N] = A[M,K] * W[N,K]^T ----------------
template<int MODE> // 0: f32 out, 1: bf16 out + f32 bias
__device__ __forceinline__ void gemm_core(const u16* A, int lda, const u16* W, int ldw,
    float* Cf, u16* Cb, int ldc, const float* bias, int K, int bm, int bn)
{
  __shared__ u16 Al[128*32];
  __shared__ u16 Wl[128*32];
  const int tid = threadIdx.x, lane = tid&63, wv = tid>>6;
  const int wm = wv>>1, wn = wv&1;
  const int fr = lane&15, fq = lane>>4;
  const int lrow = lane>>2;
  const int lcol = (lane&3)*8;
  f32x4 acc[4][4] = {};
  for(int k0=0;k0<K;k0+=32){
    #pragma unroll
    for(int r=0;r<2;++r){
      int c = wv + 4*r;
      int row = c*16 + lrow;
      const u16* ga = A + (size_t)(bm+row)*lda + k0 + lcol;
      const u16* gw = W + (size_t)(bn+row)*ldw + k0 + lcol;
      GL2LDS(ga, &Al[c*512]);
      GL2LDS(gw, &Wl[c*512]);
    }
    __syncthreads();
    short8 af[4], bfr[4];
    #pragma unroll
    for(int m=0;m<4;++m) af[m] = *(const short8*)&Al[(wm*64 + m*16 + fr)*32 + fq*8];
    #pragma unroll
    for(int n=0;n<4;++n) bfr[n] = *(const short8*)&Wl[(wn*64 + n*16 + fr)*32 + fq*8];
    #pragma unroll
    for(int m=0;m<4;++m)
      #pragma unroll
      for(int n=0;n<4;++n)
        acc[m][n] = __builtin_amdgcn_mfma_f32_16x16x32_bf16(af[m], bfr[n], acc[m][n], 0,0,0);
    __syncthreads();
  }
  #pragma unroll
  for(int m=0;m<4;++m)
    #pragma unroll
    for(int n=0;n<4;++n)
      #pragma unroll
      for(int i=0;i<4;++i){
        int row = bm + wm*64 + m*16 + fq*4 + i;
        int col = bn + wn*64 + n*16 + fr;
        if(MODE==0) Cf[(size_t)row*ldc + col] = acc[m][n][i];
        else        Cb[(size_t)row*ldc + col] = f2bf(acc[m][n][i] + bias[col]);
      }
}

__global__ __launch_bounds__(256) void k_proj(const u16* tgt, const u16* s1, const u16* s2,
    const u16* w1, const u16* w2, float* sq1, float* sk1, float* sq2, float* sk2)
{
  int z = blockIdx.z;
  int Mt = (z&1) ? 1024 : 512;
  int bm = blockIdx.y*128; if(bm >= Mt) return;
  const u16* A = (z&1) ? ((z>>1) ? s2 : s1) : tgt;
  const u16* W = ((z>>1) ? w2 : w1) + ((z&1) ? TDIM : 0);
  float* Cf = (z==0) ? sq1 : (z==1) ? sk1 : (z==2) ? sq2 : sk2;
  gemm_core<0>(A, TDIM, W, 2*TDIM, Cf, nullptr, TDIM, nullptr, TDIM, bm, blockIdx.x*128);
}

__global__ __launch_bounds__(256) void k_big(const u16* tgt, const u16* W, const float* bias, u16* logits)
{
  gemm_core<1>(tgt, TDIM, W, TDIM, nullptr, logits, NV, bias, TDIM, blockIdx.x*128, blockIdx.y*128);
}

// ---------------- scores + softmax + att-LN + weighted sum, one block per (src,bt) ----------------
__global__ __launch_bounds__(256) void k_score(
  const float* sq1, const float* sq2, const float* sk1, const float* sk2,
  const float* b1, const float* b2, const float* v1p, const float* v2p,
  const float* k1g, const float* k2g, const float* msk,
  float* al1, float* al2, float* c1, float* c2)
{
  // bijective XCD swizzle: 1024 blocks, same (src,b) panel -> same XCD L2
  int id = blockIdx.x;
  int wid = (id&7)*128 + (id>>3);
  int src = wid>>9, bt = wid&511, b = bt>>6;
  int tid = threadIdx.x, lane = tid&63, wv = tid>>6;
  const float* SQ = src? sq2:sq1;
  const float* SK = src? sk2:sk1;
  const float* bb = src? b2:b1;
  const float* vp = src? v2p:v1p;
  const float* kg = src? k2g:k1g;
  float* al = src? al2:al1;
  float* cc = src? c2:c1;
  const float CL = 2.8853900817779268f; // 2*log2(e)
  __shared__ float sc_s[128], aw_s[128], st_s[4];

  // lane owns e in [lane*8, lane*8+8)
  float4 q0  = *(const float4*)&SQ[(size_t)bt*512 + lane*8];
  float4 q1  = *(const float4*)&SQ[(size_t)bt*512 + lane*8 + 4];
  float4 bb0 = *(const float4*)&bb[lane*8];
  float4 bb1 = *(const float4*)&bb[lane*8 + 4];
  float4 va  = *(const float4*)&vp[lane*8];
  float4 vb  = *(const float4*)&vp[lane*8 + 4];
  float sqv[8] = {(q0.x+bb0.x)*CL,(q0.y+bb0.y)*CL,(q0.z+bb0.z)*CL,(q0.w+bb0.w)*CL,
                  (q1.x+bb1.x)*CL,(q1.y+bb1.y)*CL,(q1.z+bb1.z)*CL,(q1.w+bb1.w)*CL};
  float vv[8]  = {va.x,va.y,va.z,va.w,vb.x,vb.y,vb.z,vb.w};
  float Vsum = wsum(vv[0]+vv[1]+vv[2]+vv[3]+vv[4]+vv[5]+vv[6]+vv[7]);

  const float* skbase = SK + (size_t)b*128*512 + lane*8;
  #pragma unroll 4
  for(int j=0;j<16;++j){
    int s0 = wv*32 + j*2;
    const float* r0 = skbase + (size_t)s0*512;
    const float* r1 = r0 + 512;
    float4 sa0 = *(const float4*)r0, sa1 = *(const float4*)(r0+4);
    float4 sb0 = *(const float4*)r1, sb1 = *(const float4*)(r1+4);
    float ska[8] = {sa0.x,sa0.y,sa0.z,sa0.w,sa1.x,sa1.y,sa1.z,sa1.w};
    float skb[8] = {sb0.x,sb0.y,sb0.z,sb0.w,sb1.x,sb1.y,sb1.z,sb1.w};
    float acc0 = 0.f, acc1 = 0.f;
    #pragma unroll
    for(int e=0;e<8;++e){
      float y0 = __builtin_fmaf(ska[e], CL, sqv[e]);
      float y1 = __builtin_fmaf(skb[e], CL, sqv[e]);
      float r0v = __builtin_amdgcn_rcpf(__builtin_amdgcn_exp2f(y0) + 1.f);
      float r1v = __builtin_amdgcn_rcpf(__builtin_amdgcn_exp2f(y1) + 1.f);
      acc0 = __builtin_fmaf(vv[e], r0v, acc0);
      acc1 = __builtin_fmaf(vv[e], r1v, acc1);
    }
    acc0 = wsum(acc0); acc1 = wsum(acc1);
    if(lane==0){ sc_s[s0] = Vsum - 2.f*acc0; sc_s[s0+1] = Vsum - 2.f*acc1; }
  }
  __syncthreads();
  float qm = msk[bt];
  const float* km_g = msk + 512 + src*1024 + b*128;
  if(wv==0){
    float km0 = km_g[lane], km1 = km_g[lane+64];
    float s0v = sc_s[lane], s1v = sc_s[lane+64];
    float a0 = s0v*km0*qm, a1 = s1v*km1*qm;
    float sm = wsum(a0+a1), sqq = wsum(a0*a0+a1*a1);
    float m0 = km0!=0.f ? s0v : -1e30f;
    float m1 = km1!=0.f ? s1v : -1e30f;
    float mx = wmax(fmaxf(m0,m1));
    float e0 = km0!=0.f ? __expf(s0v-mx) : 0.f;
    float e1 = km1!=0.f ? __expf(s1v-mx) : 0.f;
    float den = wsum(e0+e1);
    if(lane==0){
      float mean = sm/128.f;
      float var  = sqq/128.f - mean*mean;
      st_s[0]=mean; st_s[1]=rsqrtf(var+LNEPS); st_s[2]=mx; st_s[3]=den;
    }
  }
  __syncthreads();
  if(tid<128){
    float km = km_g[tid];
    float sc = sc_s[tid];
    float av = sc*km*qm;
    al[(size_t)bt*128 + tid] = (av-st_s[0])*st_s[1];
    aw_s[tid] = km!=0.f ? __expf(sc-st_s[2])/st_s[3] : 0.f;
  }
  __syncthreads();
  {
    int d = tid; float a0=0.f, a1=0.f;
    const float* kb = kg + (size_t)b*128*512;
    #pragma unroll 8
    for(int s=0;s<128;++s){
      float w = aw_s[s];
      a0 = __builtin_fmaf(w, kb[(size_t)s*512 + d], a0);
      a1 = __builtin_fmaf(w, kb[(size_t)s*512 + d + 256], a1);
    }
    cc[(size_t)bt*512 + d] = qm*a0;
    cc[(size_t)bt*512 + d + 256] = qm*a1;
  }
}

// ---------------- gate: p = softmax(gate_w @ [tgt,c1,c2] + gate_b) ----------------
__global__ __launch_bounds__(64) void k_gate(const float* tgt, const float* c1, const float* c2,
    const float* gw, const float* gb, float* pws)
{
  int bt = blockIdx.x, lane = threadIdx.x;
  float gl[3];
  #pragma unroll
  for(int p=0;p<3;++p){
    float acc = 0.f;
    const float* gp = gw + p*1536;
    #pragma unroll
    for(int r=0;r<8;++r){ int d=lane+64*r; acc = __builtin_fmaf(gp[d],      tgt[(size_t)bt*512+d], acc); }
    #pragma unroll
    for(int r=0;r<8;++r){ int d=lane+64*r; acc = __builtin_fmaf(gp[512+d],  c1[(size_t)bt*512+d],  acc); }
    #pragma unroll
    for(int r=0;r<8;++r){ int d=lane+64*r; acc = __builtin_fmaf(gp[1024+d], c2[(size_t)bt*512+d],  acc); }
    gl[p] = wsum(acc) + gb[p];
  }
  if(lane==0){
    float m = fmaxf(gl[0], fmaxf(gl[1], gl[2]));
    float e0=__expf(gl[0]-m), e1=__expf(gl[1]-m), e2=__expf(gl[2]-m);
    float s = e0+e1+e2;
    pws[bt*4+0]=e0/s; pws[bt*4+1]=e1/s; pws[bt*4+2]=e2/s;
  }
}

// ---------------- logits row stats ----------------
__global__ __launch_bounds__(256) void k_stats(const u16* logits, float* stats){
  int row = blockIdx.x, tid = threadIdx.x, lane = tid&63, wv = tid>>6;
  const u16* Lr = logits + (size_t)row*NV;
  float s=0.f, ss=0.f;
  for(int vb=tid; vb<NV/8; vb+=256){
    short8 x = *(const short8*)&Lr[vb*8];
    #pragma unroll
    for(int j=0;j<8;++j){ float f = bf2f((u16)x[j]); s += f; ss += f*f; }
  }
  __shared__ float rs[4], rss[4];
  s = wsum(s); ss = wsum(ss);
  if(lane==0){ rs[wv]=s; rss[wv]=ss; }
  __syncthreads();
  if(tid==0){
    float S=rs[0]+rs[1]+rs[2]+rs[3], SS=rss[0]+rss[1]+rss[2]+rss[3];
    float mean = S/(float)NV;
    float var  = SS/(float)NV - mean*mean;
    stats[row*2]   = mean;
    stats[row*2+1] = rsqrtf(var+LNEPS);
  }
}

// ---------------- final: out = p0 * LN(logits), pad zeros (f32 out) ----------------
__global__ __launch_bounds__(256) void k_final(const u16* logits, const float* stats, const float* pws, float* out){
  int gid = blockIdx.x*256 + threadIdx.x;
  int row = gid / (NEXT/4);
  int e0  = (gid % (NEXT/4))*4;
  float4 r;
  if(e0 < NV){
    float mean = stats[row*2], inv = stats[row*2+1], p0 = pws[row*4];
    const u16* L = &logits[(size_t)row*NV + e0];
    r.x = p0*(bf2f(L[0])-mean)*inv;
    r.y = p0*(bf2f(L[1])-mean)*inv;
    r.z = p0*(bf2f(L[2])-mean)*inv;
    r.w = p0*(bf2f(L[3])-mean)*inv;
  } else {
    r.x = r.y = r.z = r.w = 0.f;
  }
  *(float4*)&out[(size_t)row*NEXT + e0] = r;
}

// ---------------- scatter patch ----------------
__global__ __launch_bounds__(256) void k_scatter(const int* map1, const int* map2,
   const float* attln1, const float* attln2, const float* pws, float* out){
  int bt = blockIdx.x, b = bt>>6, i = threadIdx.x;
  __shared__ int e_s[256]; __shared__ float v_s[256];
  int src = i>>7, s = i&127;
  int e = (src ? map2 : map1)[b*128 + s];
  float val = pws[bt*4 + 1 + src] * (src ? attln2 : attln1)[(size_t)bt*128 + s];
  e_s[i] = e; v_s[i] = val;
  __syncthreads();
  bool leader = true;
  for(int j=0;j<i;++j) if(e_s[j]==e){ leader=false; break; }
  if(leader){
    float tot = 0.f;
    for(int j=i;j<256;++j) if(e_s[j]==e) tot += v_s[j];
    out[(size_t)bt*NEXT + e] += tot;
  }
}

extern "C" void kernel_launch(void* const* d_in, const int* in_sizes, int n_in,
                              void* d_out, int out_size, void* d_ws, size_t ws_size,
                              hipStream_t stream)
{
  const float* tgt  = (const float*)d_in[0];
  const float* s1k  = (const float*)d_in[1];
  const float* s2k  = (const float*)d_in[2];
  const int*   map1 = (const int*)d_in[3];
  const int*   map2 = (const int*)d_in[4];
  const float* ofw  = (const float*)d_in[5];
  const float* ofb  = (const float*)d_in[6];
  const float* a1w  = (const float*)d_in[7];
  const float* a1b  = (const float*)d_in[8];
  const float* v1   = (const float*)d_in[9];
  const float* a2w  = (const float*)d_in[10];
  const float* a2b  = (const float*)d_in[11];
  const float* v2   = (const float*)d_in[12];
  const float* gw   = (const float*)d_in[13];
  const float* gb   = (const float*)d_in[14];

  float* wsf   = (float*)d_ws;
  float* sq1   = wsf;                   // 262144
  float* sq2   = wsf + 262144;
  float* sk1   = wsf + 524288;          // 524288
  float* sk2   = wsf + 1048576;
  float* al1   = wsf + 1572864;         // 65536
  float* al2   = wsf + 1638400;
  float* pws   = wsf + 1703936;         // 2048
  float* msk   = wsf + 1705984;         // 2560
  float* stats = wsf + 1708544;         // 1024
  float* c1    = wsf + 1709568;         // 262144
  float* c2    = wsf + 1971712;         // 262144
  u16*  logits = (u16*)(wsf + 2233856); // 512*32000 bf16 = 8192000 f32-slots
  u16*  tgtb   = (u16*)(wsf + 10425856);
  u16*  s1b    = (u16*)(wsf + 10556928);
  u16*  s2b    = (u16*)(wsf + 10819072);
  u16*  a1wb   = (u16*)(wsf + 11081216);
  u16*  a2wb   = (u16*)(wsf + 11343360);
  u16*  ofwb   = (u16*)(wsf + 11605504); // + 8192000 f32 -> ends ~79 MB
  float* out   = (float*)d_out;

  k_cast   <<<9152, 256, 0, stream>>>(tgt, s1k, s2k, a1w, a2w, ofw, tgtb, s1b, s2b, a1wb, a2wb, ofwb);
  k_masks  <<<640, 256, 0, stream>>>(tgt, s1k, s2k, msk);
  k_proj   <<<dim3(4,8,4), 256, 0, stream>>>(tgtb, s1b, s2b, a1wb, a2wb, sq1, sk1, sq2, sk2);
  k_big    <<<dim3(4,250), 256, 0, stream>>>(tgtb, ofwb, ofb, logits);
  k_score  <<<1024, 256, 0, stream>>>(sq1, sq2, sk1, sk2, a1b, a2b, v1, v2, s1k, s2k, msk, al1, al2, c1, c2);
  k_gate   <<<512, 64, 0, stream>>>(tgt, c1, c2, gw, gb, pws);
  k_stats  <<<512, 256, 0, stream>>>(logits, stats);
  k_final  <<<NBT*(NEXT/4)/256, 256, 0, stream>>>(logits, stats, pws, out);
  k_scatter<<<512, 256, 0, stream>>>(map1, map2, al1, al2, pws, out);
}

// Round 5
// 154.325 us; speedup vs baseline: 1.3098x; 1.0002x over previous
//
#include <hip/hip_runtime.h>

#define NB 8
#define NT 64
#define NS 128
#define TDIM 512
#define NV 32000
#define NEXT 32256
#define NBT 512
#define LNEPS 1e-5f
#define CLG 2.8853900817779268f  // 2*log2(e)

typedef unsigned short u16;
typedef __attribute__((ext_vector_type(8))) short short8;
typedef __attribute__((ext_vector_type(4))) float f32x4;

__device__ __forceinline__ float bf2f(u16 u){ union{unsigned int i; float f;} v; v.i = ((unsigned int)u)<<16; return v.f; }
__device__ __forceinline__ u16 f2bf(float f){ union{float f; unsigned int i;} v; v.f=f; unsigned int r = v.i + 0x7FFFu + ((v.i>>16)&1u); return (u16)(r>>16); }
__device__ __forceinline__ float wsum(float v){
  v += __shfl_xor(v,32); v += __shfl_xor(v,16); v += __shfl_xor(v,8);
  v += __shfl_xor(v,4);  v += __shfl_xor(v,2);  v += __shfl_xor(v,1); return v; }
__device__ __forceinline__ float wmax(float v){
  v = fmaxf(v,__shfl_xor(v,32)); v = fmaxf(v,__shfl_xor(v,16)); v = fmaxf(v,__shfl_xor(v,8));
  v = fmaxf(v,__shfl_xor(v,4));  v = fmaxf(v,__shfl_xor(v,2));  v = fmaxf(v,__shfl_xor(v,1)); return v; }

#define GL2LDS(gp, lp) __builtin_amdgcn_global_load_lds( \
    (__attribute__((address_space(1))) void*)(void*)(gp), \
    (__attribute__((address_space(3))) void*)(void*)(lp), 16, 0, 0)

// ---------------- f32 -> bf16 cast of GEMM operands + fused masks ----------------
__global__ __launch_bounds__(256) void k_cast(const float* tgt, const float* s1, const float* s2,
    const float* a1w, const float* a2w, const float* ofw,
    u16* tgtb, u16* s1b, u16* s2b, u16* a1wb, u16* a2wb, u16* ofwb, float* msk)
{
  int blk = blockIdx.x;
  const float* src; u16* dst; int base;
  if(blk < 128){       src=tgt; dst=tgtb;  base=blk; }
  else if(blk < 384){  src=s1;  dst=s1b;   base=blk-128; }
  else if(blk < 640){  src=s2;  dst=s2b;   base=blk-384; }
  else if(blk < 896){  src=a1w; dst=a1wb;  base=blk-640; }
  else if(blk < 1152){ src=a2w; dst=a2wb;  base=blk-896; }
  else {               src=ofw; dst=ofwb;  base=blk-1152; }
  size_t off = (size_t)base*2048 + (size_t)threadIdx.x*8;
  float4 x0 = *(const float4*)(src+off);
  float4 x1 = *(const float4*)(src+off+4);
  float xs[8] = {x0.x,x0.y,x0.z,x0.w,x1.x,x1.y,x1.z,x1.w};
  short8 r;
  #pragma unroll
  for(int j=0;j<8;++j) r[j] = (short)f2bf(xs[j]);
  *(short8*)(dst+off) = r;
  if(blk < 640){
    // fused row-mask: wave w == row (tid>>6), 64 lanes cover the 512-elem row
    float a = 0.f;
    #pragma unroll
    for(int j=0;j<8;++j) a += fabsf(xs[j]);
    a = wsum(a);
    if((threadIdx.x&63)==0){
      int w = threadIdx.x>>6;
      int midx;
      if(blk<128)      midx = blk*4 + w;
      else if(blk<384) midx = 512 + (blk-128)*4 + w;
      else             midx = 1536 + (blk-384)*4 + w;
      msk[midx] = (a>0.f) ? 1.f : 0.f;
    }
  }
}

// ---------------- MFMA GEMM core: C[M,N] = A[M,K] * W[N,K]^T ----------------
// MODE 0: f32 raw; MODE 1: bf16 + f32 bias; MODE 2: f32 (acc + bias?)*scale
template<int MODE>
__device__ __forceinline__ void gemm_core(const u16* A, int lda, const u16* W, int ldw,
    float* Cf, u16* Cb, int ldc, const float* bias, int K, int bm, int bn, float scale)
{
  __shared__ u16 Al[128*32];
  __shared__ u16 Wl[128*32];
  const int tid = threadIdx.x, lane = tid&63, wv = tid>>6;
  const int wm = wv>>1, wn = wv&1;
  const int fr = lane&15, fq = lane>>4;
  const int lrow = lane>>2;
  const int lcol = (lane&3)*8;
  f32x4 acc[4][4] = {};
  for(int k0=0;k0<K;k0+=32){
    #pragma unroll
    for(int r=0;r<2;++r){
      int c = wv + 4*r;
      int row = c*16 + lrow;
      const u16* ga = A + (size_t)(bm+row)*lda + k0 + lcol;
      const u16* gw = W + (size_t)(bn+row)*ldw + k0 + lcol;
      GL2LDS(ga, &Al[c*512]);
      GL2LDS(gw, &Wl[c*512]);
    }
    __syncthreads();
    short8 af[4], bfr[4];
    #pragma unroll
    for(int m=0;m<4;++m) af[m] = *(const short8*)&Al[(wm*64 + m*16 + fr)*32 + fq*8];
    #pragma unroll
    for(int n=0;n<4;++n) bfr[n] = *(const short8*)&Wl[(wn*64 + n*16 + fr)*32 + fq*8];
    #pragma unroll
    for(int m=0;m<4;++m)
      #pragma unroll
      for(int n=0;n<4;++n)
        acc[m][n] = __builtin_amdgcn_mfma_f32_16x16x32_bf16(af[m], bfr[n], acc[m][n], 0,0,0);
    __syncthreads();
  }
  #pragma unroll
  for(int m=0;m<4;++m)
    #pragma unroll
    for(int n=0;n<4;++n)
      #pragma unroll
      for(int i=0;i<4;++i){
        int row = bm + wm*64 + m*16 + fq*4 + i;
        int col = bn + wn*64 + n*16 + fr;
        if(MODE==0) Cf[(size_t)row*ldc + col] = acc[m][n][i];
        else if(MODE==1) Cb[(size_t)row*ldc + col] = f2bf(acc[m][n][i] + bias[col]);
        else { float bv = bias ? bias[col] : 0.f; Cf[(size_t)row*ldc + col] = (acc[m][n][i] + bv)*scale; }
      }
}

__global__ __launch_bounds__(256) void k_proj(const u16* tgt, const u16* s1, const u16* s2,
    const u16* w1, const u16* w2, const float* b1, const float* b2,
    float* sq1, float* sk1, float* sq2, float* sk2)
{
  int z = blockIdx.z;
  int Mt = (z&1) ? 1024 : 512;
  int bm = blockIdx.y*128; if(bm >= Mt) return;
  const u16* A = (z&1) ? ((z>>1) ? s2 : s1) : tgt;
  const u16* W = ((z>>1) ? w2 : w1) + ((z&1) ? TDIM : 0);
  float* Cf = (z==0) ? sq1 : (z==1) ? sk1 : (z==2) ? sq2 : sk2;
  const float* bias = (z&1) ? nullptr : ((z>>1) ? b2 : b1);
  gemm_core<2>(A, TDIM, W, 2*TDIM, Cf, nullptr, TDIM, bias, TDIM, bm, blockIdx.x*128, CLG);
}

__global__ __launch_bounds__(256) void k_big(const u16* tgt, const u16* W, const float* bias, u16* logits)
{
  // bijective XCD swizzle (1000 % 8 == 0): same W n-panel's 4 m-blocks -> same XCD
  int lid = (blockIdx.x&7)*125 + (blockIdx.x>>3);
  int bm = (lid&3)*128, bn = (lid>>2)*128;
  gemm_core<1>(tgt, TDIM, W, TDIM, nullptr, logits, NV, bias, TDIM, bm, bn, 1.f);
}

// ---------------- energy: pene = sum_e v[e]*sigmoid-term, reduction-free ----------------
// grid 512: (src, b, tchunk16, schunk32, ehalf); thread owns (s, t, t+8) pair; e-half of 256.
__global__ __launch_bounds__(256) void k_energy(
  const float* sq1, const float* sq2, const float* sk1, const float* sk2,
  const float* v1p, const float* v2p, float* pene)
{
  int lid = (blockIdx.x&7)*64 + (blockIdx.x>>3);  // bijective, 512%8==0
  int src = lid>>8, b = (lid>>5)&7, tc = (lid>>3)&3, sc = (lid>>1)&3, eh = lid&1;
  int tid = threadIdx.x;
  const float* SQ = src? sq2:sq1;
  const float* SK = src? sk2:sk1;
  const float* vp = src? v2p:v1p;
  int t0 = tc*16, s0 = sc*32;
  int strow = tid&31, trow = tid>>5;

  __shared__ float sk_lds[32*65];
  float acc_a = 0.f, acc_b = 0.f;
  const float* sqa = SQ + (size_t)(b*64 + t0 + trow)*512;
  const float* sqb = sqa + 8*512;

  for(int ec=eh*4; ec<eh*4+4; ++ec){
    // stage skCL[32][64] -> lds[32][65] (b32 stores; banks (row+e)%32 conflict-free)
    {
      int r = tid>>3, c0 = (tid&7)*8;
      const float* sp = SK + (size_t)(b*128 + s0 + r)*512 + ec*64 + c0;
      float4 A0 = *(const float4*)sp;
      float4 A1 = *(const float4*)(sp+4);
      float* dp = &sk_lds[r*65 + c0];
      dp[0]=A0.x; dp[1]=A0.y; dp[2]=A0.z; dp[3]=A0.w;
      dp[4]=A1.x; dp[5]=A1.y; dp[6]=A1.z; dp[7]=A1.w;
    }
    __syncthreads();
    #pragma unroll
    for(int sub=0; sub<4; ++sub){
      int e0 = ec*64 + sub*16;
      float4 V0 = *(const float4*)(vp+e0),    V1 = *(const float4*)(vp+e0+4);
      float4 V2 = *(const float4*)(vp+e0+8),  V3 = *(const float4*)(vp+e0+12);
      float4 QA0 = *(const float4*)(sqa+e0),  QA1 = *(const float4*)(sqa+e0+4);
      float4 QA2 = *(const float4*)(sqa+e0+8),QA3 = *(const float4*)(sqa+e0+12);
      float4 QB0 = *(const float4*)(sqb+e0),  QB1 = *(const float4*)(sqb+e0+4);
      float4 QB2 = *(const float4*)(sqb+e0+8),QB3 = *(const float4*)(sqb+e0+12);
      float vv[16] = {V0.x,V0.y,V0.z,V0.w,V1.x,V1.y,V1.z,V1.w,V2.x,V2.y,V2.z,V2.w,V3.x,V3.y,V3.z,V3.w};
      float qa[16] = {QA0.x,QA0.y,QA0.z,QA0.w,QA1.x,QA1.y,QA1.z,QA1.w,QA2.x,QA2.y,QA2.z,QA2.w,QA3.x,QA3.y,QA3.z,QA3.w};
      float qb[16] = {QB0.x,QB0.y,QB0.z,QB0.w,QB1.x,QB1.y,QB1.z,QB1.w,QB2.x,QB2.y,QB2.z,QB2.w,QB3.x,QB3.y,QB3.z,QB3.w};
      const float* skr = &sk_lds[strow*65 + sub*16];
      #pragma unroll
      for(int e=0;e<16;++e){
        float skv = skr[e];
        float ya = qa[e] + skv;
        float yb = qb[e] + skv;
        float ra = __builtin_amdgcn_rcpf(__builtin_amdgcn_exp2f(ya) + 1.f);
        float rb = __builtin_amdgcn_rcpf(__builtin_amdgcn_exp2f(yb) + 1.f);
        acc_a = __builtin_fmaf(vv[e], ra, acc_a);
        acc_b = __builtin_fmaf(vv[e], rb, acc_b);
      }
    }
    __syncthreads();
  }
  size_t ia = (size_t)((eh*2+src)*512 + b*64 + t0 + trow)*128 + s0 + strow;
  pene[ia] = acc_a;
  pene[ia + 8*128] = acc_b;
}

// ---------------- softmax + att-LN + weighted sum, block per (src,b,4t) ----------------
__global__ __launch_bounds__(256) void k_sm(
  const float* pene, const float* v1p, const float* v2p,
  const float* k1g, const float* k2g, const float* msk,
  float* al1, float* al2, float* c1, float* c2)
{
  int lid = (blockIdx.x&7)*32 + (blockIdx.x>>3);  // bijective, 256%8==0
  int src = lid>>7, b = (lid>>4)&7, tq = lid&15;
  int tid = threadIdx.x, lane = tid&63, wv = tid>>6;
  int t = tq*4 + wv, bt = b*64 + t;
  const float* vp = src? v2p:v1p;
  const float* kg = src? k2g:k1g;
  float* al = src? al2:al1;
  float* cc = src? c2:c1;
  const float* km_g = msk + 512 + src*1024 + b*128;
  __shared__ float aw_lds[4][132];
  __shared__ float qm_lds[4];

  // per-wave: scores for row t, stats, al write, aw to LDS
  {
    float vsp = 0.f;
    #pragma unroll
    for(int r2=0;r2<8;++r2) vsp += vp[lane + 64*r2];
    float Vsum = wsum(vsp);
    float qm = msk[bt];
    float km0 = km_g[lane], km1 = km_g[lane+64];
    size_t pbase = (size_t)(src*512 + bt)*128;
    float s0v = Vsum - 2.f*(pene[pbase + lane]      + pene[pbase + 131072 + lane]);
    float s1v = Vsum - 2.f*(pene[pbase + lane + 64] + pene[pbase + 131072 + lane + 64]);
    float a0 = s0v*km0*qm, a1 = s1v*km1*qm;
    float sm = wsum(a0+a1), sqq = wsum(a0*a0+a1*a1);
    float m0 = km0!=0.f ? s0v : -1e30f;
    float m1 = km1!=0.f ? s1v : -1e30f;
    float mx = wmax(fmaxf(m0,m1));
    float e0 = km0!=0.f ? __expf(s0v-mx) : 0.f;
    float e1 = km1!=0.f ? __expf(s1v-mx) : 0.f;
    float den = wsum(e0+e1);
    float mean = sm/128.f;
    float inv  = rsqrtf(sqq/128.f - mean*mean + LNEPS);
    al[(size_t)bt*128 + lane]      = (a0-mean)*inv;
    al[(size_t)bt*128 + lane + 64] = (a1-mean)*inv;
    aw_lds[wv][lane]      = e0/den;
    aw_lds[wv][lane+64]   = e1/den;
    if(lane==0) qm_lds[wv] = qm;
  }
  __syncthreads();
  // weight: c[t,d] = qm * sum_s aw[t][s]*kg[b*128+s][d], thread owns d=tid, tid+256
  {
    float acc[4][2] = {};
    const float* kb = kg + (size_t)b*128*512;
    for(int s=0;s<128;++s){
      float kv0 = kb[(size_t)s*512 + tid];
      float kv1 = kb[(size_t)s*512 + tid + 256];
      #pragma unroll
      for(int w=0;w<4;++w){
        float a = aw_lds[w][s];
        acc[w][0] = __builtin_fmaf(a, kv0, acc[w][0]);
        acc[w][1] = __builtin_fmaf(a, kv1, acc[w][1]);
      }
    }
    #pragma unroll
    for(int w=0;w<4;++w){
      float qm = qm_lds[w];
      size_t o = (size_t)(b*64 + tq*4 + w)*512;
      cc[o + tid]       = qm*acc[w][0];
      cc[o + tid + 256] = qm*acc[w][1];
    }
  }
}

// ---------------- gate: p = softmax(gate_w @ [tgt,c1,c2] + gate_b) ----------------
__global__ __launch_bounds__(64) void k_gate(const float* tgt, const float* c1, const float* c2,
    const float* gw, const float* gb, float* pws)
{
  int bt = blockIdx.x, lane = threadIdx.x;
  float gl[3];
  #pragma unroll
  for(int p=0;p<3;++p){
    float acc = 0.f;
    const float* gp = gw + p*1536;
    #pragma unroll
    for(int r=0;r<8;++r){ int d=lane+64*r; acc = __builtin_fmaf(gp[d],      tgt[(size_t)bt*512+d], acc); }
    #pragma unroll
    for(int r=0;r<8;++r){ int d=lane+64*r; acc = __builtin_fmaf(gp[512+d],  c1[(size_t)bt*512+d],  acc); }
    #pragma unroll
    for(int r=0;r<8;++r){ int d=lane+64*r; acc = __builtin_fmaf(gp[1024+d], c2[(size_t)bt*512+d],  acc); }
    gl[p] = wsum(acc) + gb[p];
  }
  if(lane==0){
    float m = fmaxf(gl[0], fmaxf(gl[1], gl[2]));
    float e0=__expf(gl[0]-m), e1=__expf(gl[1]-m), e2=__expf(gl[2]-m);
    float s = e0+e1+e2;
    pws[bt*4+0]=e0/s; pws[bt*4+1]=e1/s; pws[bt*4+2]=e2/s;
  }
}

// ---------------- logits row stats ----------------
__global__ __launch_bounds__(256) void k_stats(const u16* logits, float* stats){
  int row = blockIdx.x, tid = threadIdx.x, lane = tid&63, wv = tid>>6;
  const u16* Lr = logits + (size_t)row*NV;
  float s=0.f, ss=0.f;
  for(int vb=tid; vb<NV/8; vb+=256){
    short8 x = *(const short8*)&Lr[vb*8];
    #pragma unroll
    for(int j=0;j<8;++j){ float f = bf2f((u16)x[j]); s += f; ss += f*f; }
  }
  __shared__ float rs[4], rss[4];
  s = wsum(s); ss = wsum(ss);
  if(lane==0){ rs[wv]=s; rss[wv]=ss; }
  __syncthreads();
  if(tid==0){
    float S=rs[0]+rs[1]+rs[2]+rs[3], SS=rss[0]+rss[1]+rss[2]+rss[3];
    float mean = S/(float)NV;
    float var  = SS/(float)NV - mean*mean;
    stats[row*2]   = mean;
    stats[row*2+1] = rsqrtf(var+LNEPS);
  }
}

// ---------------- final: out = p0 * LN(logits), pad zeros (f32 out) ----------------
__global__ __launch_bounds__(256) void k_final(const u16* logits, const float* stats, const float* pws, float* out){
  int gid = blockIdx.x*256 + threadIdx.x;
  int row = gid / (NEXT/4);
  int e0  = (gid % (NEXT/4))*4;
  float4 r;
  if(e0 < NV){
    float mean = stats[row*2], inv = stats[row*2+1], p0 = pws[row*4];
    const u16* L = &logits[(size_t)row*NV + e0];
    r.x = p0*(bf2f(L[0])-mean)*inv;
    r.y = p0*(bf2f(L[1])-mean)*inv;
    r.z = p0*(bf2f(L[2])-mean)*inv;
    r.w = p0*(bf2f(L[3])-mean)*inv;
  } else {
    r.x = r.y = r.z = r.w = 0.f;
  }
  *(float4*)&out[(size_t)row*NEXT + e0] = r;
}

// ---------------- scatter patch ----------------
__global__ __launch_bounds__(256) void k_scatter(const int* map1, const int* map2,
   const float* attln1, const float* attln2, const float* pws, float* out){
  int bt = blockIdx.x, b = bt>>6, i = threadIdx.x;
  __shared__ int e_s[256]; __shared__ float v_s[256];
  int src = i>>7, s = i&127;
  int e = (src ? map2 : map1)[b*128 + s];
  float val = pws[bt*4 + 1 + src] * (src ? attln2 : attln1)[(size_t)bt*128 + s];
  e_s[i] = e; v_s[i] = val;
  __syncthreads();
  bool leader = true;
  for(int j=0;j<i;++j) if(e_s[j]==e){ leader=false; break; }
  if(leader){
    float tot = 0.f;
    for(int j=i;j<256;++j) if(e_s[j]==e) tot += v_s[j];
    out[(size_t)bt*NEXT + e] += tot;
  }
}

extern "C" void kernel_launch(void* const* d_in, const int* in_sizes, int n_in,
                              void* d_out, int out_size, void* d_ws, size_t ws_size,
                              hipStream_t stream)
{
  const float* tgt  = (const float*)d_in[0];
  const float* s1k  = (const float*)d_in[1];
  const float* s2k  = (const float*)d_in[2];
  const int*   map1 = (const int*)d_in[3];
  const int*   map2 = (const int*)d_in[4];
  const float* ofw  = (const float*)d_in[5];
  const float* ofb  = (const float*)d_in[6];
  const float* a1w  = (const float*)d_in[7];
  const float* a1b  = (const float*)d_in[8];
  const float* v1   = (const float*)d_in[9];
  const float* a2w  = (const float*)d_in[10];
  const float* a2b  = (const float*)d_in[11];
  const float* v2   = (const float*)d_in[12];
  const float* gw   = (const float*)d_in[13];
  const float* gb   = (const float*)d_in[14];

  float* wsf   = (float*)d_ws;
  float* sq1   = wsf;                   // 262144
  float* sq2   = wsf + 262144;
  float* sk1   = wsf + 524288;          // 524288
  float* sk2   = wsf + 1048576;
  float* al1   = wsf + 1572864;         // 65536
  float* al2   = wsf + 1638400;
  float* pws   = wsf + 1703936;
  float* msk   = wsf + 1705984;
  float* stats = wsf + 1708544;
  float* c1    = wsf + 1709568;         // 262144
  float* c2    = wsf + 1971712;
  float* pene  = wsf + 2233856;         // 2*2*512*128 = 262144
  u16*  logits = (u16*)(wsf + 2496000); // 16384000 u16
  u16*  tgtb   = (u16*)(wsf + 10688000);
  u16*  s1b    = (u16*)(wsf + 10819072);
  u16*  s2b    = (u16*)(wsf + 11081216);
  u16*  a1wb   = (u16*)(wsf + 11343360);
  u16*  a2wb   = (u16*)(wsf + 11605504);
  u16*  ofwb   = (u16*)(wsf + 11867648); // + 8192000 f32 -> ~80 MB
  float* out   = (float*)d_out;

  k_cast   <<<9152, 256, 0, stream>>>(tgt, s1k, s2k, a1w, a2w, ofw, tgtb, s1b, s2b, a1wb, a2wb, ofwb, msk);
  k_proj   <<<dim3(4,8,4), 256, 0, stream>>>(tgtb, s1b, s2b, a1wb, a2wb, a1b, a2b, sq1, sk1, sq2, sk2);
  k_energy <<<512, 256, 0, stream>>>(sq1, sq2, sk1, sk2, v1, v2, pene);
  k_sm     <<<256, 256, 0, stream>>>(pene, v1, v2, s1k, s2k, msk, al1, al2, c1, c2);
  k_gate   <<<512, 64, 0, stream>>>(tgt, c1, c2, gw, gb, pws);
  k_big    <<<1000, 256, 0, stream>>>(tgtb, ofwb, ofb, logits);
  k_stats  <<<512, 256, 0, stream>>>(logits, stats);
  k_final  <<<NBT*(NEXT/4)/256, 256, 0, stream>>>(logits, stats, pws, out);
  k_scatter<<<512, 256, 0, stream>>>(map1, map2, al1, al2, pws, out);
}